// Round 1
// baseline (532.604 us; speedup 1.0000x reference)
//
#include <hip/hip_runtime.h>
#include <stdint.h>

// Problem constants (SeqAttnMatch): B=32, LP=2048, LQ=512, D=256, fp32 in/out.
#define B_  32
#define LP_ 2048
#define LQ_ 512
#define D_  256

typedef __attribute__((ext_vector_type(8))) short short8;   // 8 bf16 = 4 VGPRs
typedef __attribute__((ext_vector_type(4))) float f32x4;

// ---- bf16 helpers (RNE) ----
__device__ __forceinline__ ushort f2bf(float x) {
    union { float f; uint32_t u; } v; v.f = x;
    uint32_t r = v.u + 0x7FFFu + ((v.u >> 16) & 1u);
    return (ushort)(r >> 16);
}
__device__ __forceinline__ float bf2f(ushort h) {
    union { float f; uint32_t u; } v; v.u = ((uint32_t)h) << 16;
    return v.f;
}

// ---- K0a: split W (fp32 [256*256]) into hi/lo bf16 planes ----
__global__ void k_wsplit(const float* __restrict__ W,
                         ushort* __restrict__ Whi, ushort* __restrict__ Wlo) {
    int i = blockIdx.x * 256 + threadIdx.x;   // grid covers 65536
    float w = W[i];
    ushort h = f2bf(w);
    Whi[i] = h;
    Wlo[i] = f2bf(w - bf2f(h));
}

// ---- K0b: transpose y [B][LQ][D] f32 -> yT [B][D][LQ] bf16 ----
__global__ void k_ytrans(const float* __restrict__ y, ushort* __restrict__ yT) {
    __shared__ float tile[32][33];
    int bid = blockIdx.x;            // B*16*8 = 4096 blocks
    int b  = bid >> 7;
    int t2 = bid & 127;
    int qt = t2 >> 3;                // 0..15 (q tiles of 32)
    int dt = t2 & 7;                 // 0..7  (d tiles of 32)
    int q0 = qt * 32, d0 = dt * 32;
    int tid = threadIdx.x;
    int r  = tid >> 3;               // 0..31
    int c4 = (tid & 7) * 4;          // 0..28
    float4 v = *(const float4*)(y + ((size_t)(b * LQ_ + q0 + r) * D_ + d0 + c4));
    tile[r][c4 + 0] = v.x; tile[r][c4 + 1] = v.y;
    tile[r][c4 + 2] = v.z; tile[r][c4 + 3] = v.w;
    __syncthreads();
    // out row d = d0+r, cols q0+c4..+3 ; yT[d][q] = y[q][d] = tile[q_local][d_local]
    ushort4 o;
    o.x = f2bf(tile[c4 + 0][r]);
    o.y = f2bf(tile[c4 + 1][r]);
    o.z = f2bf(tile[c4 + 2][r]);
    o.w = f2bf(tile[c4 + 3][r]);
    *(ushort4*)(yT + ((size_t)(b * D_ + d0 + r) * LQ_ + q0 + c4)) = o;
}

// ---- K1/K2: proj = relu(A @ W^T + b), split-bf16 MFMA (hi*hi + hi*lo + lo*hi) ----
// Block: 256 thr (4 waves), 64 rows/block, full N=256. Wave w owns rows 16w..16w+15.
template <bool SPLIT>
__global__ __launch_bounds__(256) void k_proj(const float* __restrict__ A,
                                              const ushort* __restrict__ Whi,
                                              const ushort* __restrict__ Wlo,
                                              const float* __restrict__ bias,
                                              float* __restrict__ Of32,
                                              ushort* __restrict__ Ohi,
                                              ushort* __restrict__ Olo) {
    __shared__ ushort Wh_s[256 * 40];   // rows padded to 40 (bank-conflict-free b128 reads)
    __shared__ ushort Wl_s[256 * 40];
    const int tid  = threadIdx.x;
    const int w    = tid >> 6;
    const int L    = tid & 63;
    const int c    = L & 15;
    const int quad = L >> 4;
    const int row0 = blockIdx.x * 64;
    const int arow = row0 + w * 16 + c;      // A-frag row for this lane

    f32x4 acc[16];
#pragma unroll
    for (int i = 0; i < 16; i++) acc[i] = (f32x4)0.f;

    for (int kc = 0; kc < 8; kc++) {
        __syncthreads();
        // stage W chunk [256 e][32 k] hi & lo into LDS
        {
            int e0  = tid >> 2;      // 0..63
            int seg = tid & 3;       // 16B segment
#pragma unroll
            for (int pass = 0; pass < 4; pass++) {
                int ee = e0 + pass * 64;
                short8 vh = *(const short8*)(Whi + ee * 256 + kc * 32 + seg * 8);
                short8 vl = *(const short8*)(Wlo + ee * 256 + kc * 32 + seg * 8);
                *(short8*)(Wh_s + ee * 40 + seg * 8) = vh;
                *(short8*)(Wl_s + ee * 40 + seg * 8) = vl;
            }
        }
        __syncthreads();
        // A-frag: 8 fp32 -> hi/lo bf16
        float4 x0 = *(const float4*)(A + (size_t)arow * 256 + kc * 32 + quad * 8);
        float4 x1 = *(const float4*)(A + (size_t)arow * 256 + kc * 32 + quad * 8 + 4);
        float xs[8] = {x0.x, x0.y, x0.z, x0.w, x1.x, x1.y, x1.z, x1.w};
        short8 ah, al;
#pragma unroll
        for (int j = 0; j < 8; j++) {
            ushort h = f2bf(xs[j]);
            ah[j] = (short)h;
            al[j] = (short)f2bf(xs[j] - bf2f(h));
        }
#pragma unroll
        for (int nt = 0; nt < 16; nt++) {
            short8 bh = *(const short8*)(Wh_s + (nt * 16 + c) * 40 + quad * 8);
            short8 bl = *(const short8*)(Wl_s + (nt * 16 + c) * 40 + quad * 8);
            acc[nt] = __builtin_amdgcn_mfma_f32_16x16x32_bf16(ah, bh, acc[nt], 0, 0, 0);
            acc[nt] = __builtin_amdgcn_mfma_f32_16x16x32_bf16(ah, bl, acc[nt], 0, 0, 0);
            acc[nt] = __builtin_amdgcn_mfma_f32_16x16x32_bf16(al, bh, acc[nt], 0, 0, 0);
        }
    }
    // epilogue: +bias, relu, store (C/D layout: row=quad*4+r, col=16nt+c)
#pragma unroll
    for (int nt = 0; nt < 16; nt++) {
        const int e = nt * 16 + c;
        const float bv = bias[e];
#pragma unroll
        for (int r = 0; r < 4; r++) {
            const int grow = row0 + w * 16 + quad * 4 + r;
            float v = acc[nt][r] + bv;
            v = fmaxf(v, 0.f);
            if (SPLIT) {
                ushort h = f2bf(v);
                Ohi[(size_t)grow * 256 + e] = h;
                Olo[(size_t)grow * 256 + e] = f2bf(v - bf2f(h));
            } else {
                Of32[(size_t)grow * 256 + e] = v;
            }
        }
    }
}

// ---- K3: fused scores (split-bf16) + softmax + match (bf16) ----
// Grid: B*32 blocks; block = (batch b, 64-row x tile). 4 waves, wave w owns rows 16w..16w+15.
__global__ __launch_bounds__(256, 2) void k_attn(const float* __restrict__ xp,
                                                 const ushort* __restrict__ yph,
                                                 const ushort* __restrict__ ypl,
                                                 const ushort* __restrict__ yT,
                                                 float* __restrict__ out) {
    __shared__ ushort alpha_s[64 * 512];   // 64KB, xor-swizzled 16B chunks
    const int tid  = threadIdx.x;
    const int w    = tid >> 6;
    const int L    = tid & 63;
    const int c    = L & 15;
    const int quad = L >> 4;
    const int bid  = blockIdx.x;
    const int b    = bid >> 5;
    const int mt   = bid & 31;
    const int m0   = mt * 64;

    // ---------- Phase A: scores [16 x 512] per wave ----------
    const int arow = b * LP_ + m0 + w * 16 + c;
    short8 ah[8], al[8];
#pragma unroll
    for (int kc = 0; kc < 8; kc++) {
        float4 x0 = *(const float4*)(xp + (size_t)arow * 256 + kc * 32 + quad * 8);
        float4 x1 = *(const float4*)(xp + (size_t)arow * 256 + kc * 32 + quad * 8 + 4);
        float xs[8] = {x0.x, x0.y, x0.z, x0.w, x1.x, x1.y, x1.z, x1.w};
#pragma unroll
        for (int j = 0; j < 8; j++) {
            ushort h = f2bf(xs[j]);
            ah[kc][j] = (short)h;
            al[kc][j] = (short)f2bf(xs[j] - bf2f(h));
        }
    }
    f32x4 sc[32];
#pragma unroll
    for (int t = 0; t < 32; t++) sc[t] = (f32x4)0.f;
#pragma unroll
    for (int t = 0; t < 32; t++) {
        const ushort* ph = yph + (size_t)(b * LQ_ + t * 16 + c) * 256;
        const ushort* pl = ypl + (size_t)(b * LQ_ + t * 16 + c) * 256;
#pragma unroll
        for (int kc = 0; kc < 8; kc++) {
            short8 bh = *(const short8*)(ph + kc * 32 + quad * 8);
            short8 bl = *(const short8*)(pl + kc * 32 + quad * 8);
            sc[t] = __builtin_amdgcn_mfma_f32_16x16x32_bf16(ah[kc], bh, sc[t], 0, 0, 0);
            sc[t] = __builtin_amdgcn_mfma_f32_16x16x32_bf16(ah[kc], bl, sc[t], 0, 0, 0);
            sc[t] = __builtin_amdgcn_mfma_f32_16x16x32_bf16(al[kc], bh, sc[t], 0, 0, 0);
        }
    }

    // ---------- Phase B: softmax over q (row = quad*4+r, col q = 16t+c) ----------
    float inv[4];
#pragma unroll
    for (int r = 0; r < 4; r++) {
        float mx = -1e30f;
#pragma unroll
        for (int t = 0; t < 32; t++) mx = fmaxf(mx, sc[t][r]);
#pragma unroll
        for (int mask = 1; mask <= 8; mask <<= 1) mx = fmaxf(mx, __shfl_xor(mx, mask));
        float s = 0.f;
#pragma unroll
        for (int t = 0; t < 32; t++) {
            float e = __expf(sc[t][r] - mx);
            sc[t][r] = e;
            s += e;
        }
#pragma unroll
        for (int mask = 1; mask <= 8; mask <<= 1) s += __shfl_xor(s, mask);
        inv[r] = 1.f / s;
    }
    // write alpha (bf16) to LDS, xor-swizzled 8-elem chunks
#pragma unroll
    for (int r = 0; r < 4; r++) {
        const int m_loc = w * 16 + quad * 4 + r;
        const int swz = m_loc & 7;
#pragma unroll
        for (int t = 0; t < 32; t++) {
            int q = t * 16 + c;
            int chunk = (q >> 3) ^ swz;
            alpha_s[m_loc * 512 + chunk * 8 + (q & 7)] = f2bf(sc[t][r] * inv[r]);
        }
    }
    __syncthreads();

    // ---------- Phase C: out[16 x 256] per wave = alpha @ y (via yT) ----------
    f32x4 oacc[16];
#pragma unroll
    for (int i = 0; i < 16; i++) oacc[i] = (f32x4)0.f;
    const int m_loc = w * 16 + c;
    const int swz = m_loc & 7;
    for (int kc = 0; kc < 16; kc++) {
        int chunk = (kc * 4 + quad) ^ swz;
        short8 af = *(const short8*)(alpha_s + m_loc * 512 + chunk * 8);
#pragma unroll
        for (int nt = 0; nt < 16; nt++) {
            short8 bf_ = *(const short8*)(yT + (size_t)(b * D_ + nt * 16 + c) * LQ_ + kc * 32 + quad * 8);
            oacc[nt] = __builtin_amdgcn_mfma_f32_16x16x32_bf16(af, bf_, oacc[nt], 0, 0, 0);
        }
    }
    // epilogue
#pragma unroll
    for (int nt = 0; nt < 16; nt++) {
        const int d = nt * 16 + c;
#pragma unroll
        for (int r = 0; r < 4; r++) {
            const int grow = m0 + w * 16 + quad * 4 + r;
            out[(size_t)(b * LP_ + grow) * 256 + d] = oacc[nt][r];
        }
    }
}

extern "C" void kernel_launch(void* const* d_in, const int* in_sizes, int n_in,
                              void* d_out, int out_size, void* d_ws, size_t ws_size,
                              hipStream_t stream) {
    const float* x    = (const float*)d_in[0];   // [32,2048,256]
    const float* y    = (const float*)d_in[1];   // [32,512,256]
    const float* W    = (const float*)d_in[2];   // [256,256]
    const float* bias = (const float*)d_in[3];   // [256]
    float* out = (float*)d_out;

    // workspace layout (needs ~88.3 MB)
    char* ws = (char*)d_ws;
    size_t off = 0;
    ushort* Whi = (ushort*)(ws + off); off += (size_t)D_ * D_ * 2;
    ushort* Wlo = (ushort*)(ws + off); off += (size_t)D_ * D_ * 2;
    ushort* yT  = (ushort*)(ws + off); off += (size_t)B_ * D_ * LQ_ * 2;
    ushort* yph = (ushort*)(ws + off); off += (size_t)B_ * LQ_ * D_ * 2;
    ushort* ypl = (ushort*)(ws + off); off += (size_t)B_ * LQ_ * D_ * 2;
    float*  xp  = (float*)(ws + off);  off += (size_t)B_ * LP_ * D_ * 4;

    k_wsplit<<<(D_ * D_) / 256, 256, 0, stream>>>(W, Whi, Wlo);
    k_ytrans<<<B_ * 128, 256, 0, stream>>>(y, yT);
    k_proj<true><<<(B_ * LQ_) / 64, 256, 0, stream>>>(y, Whi, Wlo, bias, nullptr, yph, ypl);
    k_proj<false><<<(B_ * LP_) / 64, 256, 0, stream>>>(x, Whi, Wlo, bias, xp, nullptr, nullptr);
    k_attn<<<B_ * 32, 256, 0, stream>>>(xp, yph, ypl, yT, out);
}

// Round 2
// 356.739 us; speedup vs baseline: 1.4930x; 1.4930x over previous
//
#include <hip/hip_runtime.h>
#include <stdint.h>

// Problem constants (SeqAttnMatch): B=32, LP=2048, LQ=512, D=256, fp32 in/out.
#define B_  32
#define LP_ 2048
#define LQ_ 512
#define D_  256

typedef __attribute__((ext_vector_type(8))) short short8;   // 8 bf16 = 4 VGPRs
typedef __attribute__((ext_vector_type(4))) float f32x4;

// ---- bf16 helpers (RNE) ----
__device__ __forceinline__ ushort f2bf(float x) {
    union { float f; uint32_t u; } v; v.f = x;
    uint32_t r = v.u + 0x7FFFu + ((v.u >> 16) & 1u);
    return (ushort)(r >> 16);
}
__device__ __forceinline__ float bf2f(ushort h) {
    union { float f; uint32_t u; } v; v.u = ((uint32_t)h) << 16;
    return v.f;
}

// async global->LDS, 16B per lane. ldsptr must be wave-uniform; HW writes at
// ldsptr + lane*16.
__device__ __forceinline__ void gl_lds16(const void* g, void* l) {
    __builtin_amdgcn_global_load_lds(
        (const __attribute__((address_space(1))) void*)g,
        (__attribute__((address_space(3))) void*)l, 16, 0, 0);
}

// ---- K0a: split W (fp32 [256*256]) into hi/lo bf16 planes ----
__global__ void k_wsplit(const float* __restrict__ W,
                         ushort* __restrict__ Whi, ushort* __restrict__ Wlo) {
    int i = blockIdx.x * 256 + threadIdx.x;
    float w = W[i];
    ushort h = f2bf(w);
    Whi[i] = h;
    Wlo[i] = f2bf(w - bf2f(h));
}

// ---- K0b: transpose y [B][LQ][D] f32 -> yT [B][D][LQ] bf16 ----
__global__ void k_ytrans(const float* __restrict__ y, ushort* __restrict__ yT) {
    __shared__ float tile[32][33];
    int bid = blockIdx.x;            // B*16*8 = 4096 blocks
    int b  = bid >> 7;
    int t2 = bid & 127;
    int qt = t2 >> 3;
    int dt = t2 & 7;
    int q0 = qt * 32, d0 = dt * 32;
    int tid = threadIdx.x;
    int r  = tid >> 3;
    int c4 = (tid & 7) * 4;
    float4 v = *(const float4*)(y + ((size_t)(b * LQ_ + q0 + r) * D_ + d0 + c4));
    tile[r][c4 + 0] = v.x; tile[r][c4 + 1] = v.y;
    tile[r][c4 + 2] = v.z; tile[r][c4 + 3] = v.w;
    __syncthreads();
    ushort4 o;
    o.x = f2bf(tile[c4 + 0][r]);
    o.y = f2bf(tile[c4 + 1][r]);
    o.z = f2bf(tile[c4 + 2][r]);
    o.w = f2bf(tile[c4 + 3][r]);
    *(ushort4*)(yT + ((size_t)(b * D_ + d0 + r) * LQ_ + q0 + c4)) = o;
}

// ---- K1/K2: proj = relu(A @ W^T + b), 2-term split (ah*bh + ah*bl) ----
// Block: 256 thr (4 waves), 64 rows/block. Wave w owns rows 16w..16w+15.
// W staged per-kc via global_load_lds into 32 x 1KB lane-contiguous blocks.
template <bool SPLIT>
__global__ __launch_bounds__(256) void k_proj(const float* __restrict__ A,
                                              const ushort* __restrict__ Whi,
                                              const ushort* __restrict__ Wlo,
                                              const float* __restrict__ bias,
                                              float* __restrict__ Of32,
                                              ushort* __restrict__ Ohi,
                                              ushort* __restrict__ Olo) {
    __shared__ ushort Ws[16384];   // 32KB: block i (p*16+nt) at i*512 ushorts
    const int tid  = threadIdx.x;
    const int w    = tid >> 6;
    const int L    = tid & 63;
    const int c    = L & 15;
    const int quad = L >> 4;
    const int row0 = blockIdx.x * 64;
    const int arow = row0 + w * 16 + c;

    f32x4 acc[16];
#pragma unroll
    for (int i = 0; i < 16; i++) acc[i] = (f32x4)0.f;

    for (int kc = 0; kc < 8; kc++) {
        __syncthreads();   // WAR: previous compute done
        // stage W chunk: lane L of instr i holds W[(i&15)*16 + (L&15)][kc*32 + (L>>4)*8 ..+8]
#pragma unroll
        for (int ii = 0; ii < 8; ii++) {
            int i = w * 8 + ii;
            const ushort* src = ((i >> 4) ? Wlo : Whi) +
                ((size_t)((i & 15) * 16 + c) * 256 + kc * 32 + quad * 8);
            gl_lds16(src, (char*)Ws + i * 1024);
        }
        // A-frag (overlaps staging)
        float4 x0 = *(const float4*)(A + (size_t)arow * 256 + kc * 32 + quad * 8);
        float4 x1 = *(const float4*)(A + (size_t)arow * 256 + kc * 32 + quad * 8 + 4);
        float xs[8] = {x0.x, x0.y, x0.z, x0.w, x1.x, x1.y, x1.z, x1.w};
        short8 ah;
#pragma unroll
        for (int j = 0; j < 8; j++) ah[j] = (short)f2bf(xs[j]);
        __syncthreads();   // RAW: stage complete
#pragma unroll
        for (int nt = 0; nt < 16; nt++) {
            short8 bh = *(const short8*)(Ws + nt * 512 + L * 8);
            short8 bl = *(const short8*)(Ws + (16 + nt) * 512 + L * 8);
            acc[nt] = __builtin_amdgcn_mfma_f32_16x16x32_bf16(ah, bh, acc[nt], 0, 0, 0);
            acc[nt] = __builtin_amdgcn_mfma_f32_16x16x32_bf16(ah, bl, acc[nt], 0, 0, 0);
        }
    }
#pragma unroll
    for (int nt = 0; nt < 16; nt++) {
        const int e = nt * 16 + c;
        const float bv = bias[e];
#pragma unroll
        for (int r = 0; r < 4; r++) {
            const int grow = row0 + w * 16 + quad * 4 + r;
            float v = acc[nt][r] + bv;
            v = fmaxf(v, 0.f);
            if (SPLIT) {
                ushort h = f2bf(v);
                Ohi[(size_t)grow * 256 + e] = h;
                Olo[(size_t)grow * 256 + e] = f2bf(v - bf2f(h));
            } else {
                Of32[(size_t)grow * 256 + e] = v;
            }
        }
    }
}

// ---- K3: fused scores (split-bf16) + softmax + match (bf16) ----
// Block = (batch, 64 x-rows), 4 waves. Wave (g = w&1, h = w>>1):
//   rows m0 + g*32 + [0,32), q-half h*256 + [0,256).
__global__ __launch_bounds__(256, 2) void k_attn(const float* __restrict__ xp,
                                                 const ushort* __restrict__ yph,
                                                 const ushort* __restrict__ ypl,
                                                 const ushort* __restrict__ yT,
                                                 float* __restrict__ out) {
    __shared__ ushort lds[32768];   // 64KB, reused across phases
    const int tid  = threadIdx.x;
    const int w    = tid >> 6;
    const int L    = tid & 63;
    const int c    = L & 15;
    const int quad = L >> 4;
    const int g    = w & 1;
    const int h    = w >> 1;

    // XCD-affinity swizzle: XCD x sees only batches 4x..4x+3
    const int bid = blockIdx.x;
    const int j   = bid >> 3;
    const int b   = (bid & 7) * 4 + (j >> 5);
    const int mt  = j & 31;
    const int m0  = mt * 64;

    f32x4 sc[2][16];
#pragma unroll
    for (int s = 0; s < 2; s++)
#pragma unroll
        for (int t = 0; t < 16; t++) sc[s][t] = (f32x4)0.f;

    // ---------- Phase A: scores. Outer loop over k-chunks of 32. ----------
    const size_t xbase0 = (size_t)(b * LP_ + m0 + g * 32 + c) * 256;
    const size_t xbase1 = xbase0 + 16 * 256;
    float4 cx0a = *(const float4*)(xp + xbase0 + quad * 8);
    float4 cx0b = *(const float4*)(xp + xbase0 + quad * 8 + 4);
    float4 cx1a = *(const float4*)(xp + xbase1 + quad * 8);
    float4 cx1b = *(const float4*)(xp + xbase1 + quad * 8 + 4);

    for (int kc = 0; kc < 8; kc++) {
        __syncthreads();   // WAR: previous chunk reads done
        // stage yp[all 512 q][kc*32..+32] hi+lo: 64 x 1KB blocks, i = p*32 + tq
#pragma unroll
        for (int ii = 0; ii < 16; ii++) {
            int i = w * 16 + ii;
            const ushort* src = ((i >> 5) ? ypl : yph) +
                ((size_t)(b * LQ_ + (i & 31) * 16 + c) * 256 + kc * 32 + quad * 8);
            gl_lds16(src, (char*)lds + i * 1024);
        }
        // convert current A-frags
        short8 ah0, al0, ah1, al1;
        {
            float xs0[8] = {cx0a.x, cx0a.y, cx0a.z, cx0a.w, cx0b.x, cx0b.y, cx0b.z, cx0b.w};
            float xs1[8] = {cx1a.x, cx1a.y, cx1a.z, cx1a.w, cx1b.x, cx1b.y, cx1b.z, cx1b.w};
#pragma unroll
            for (int jj = 0; jj < 8; jj++) {
                ushort h0 = f2bf(xs0[jj]);
                ah0[jj] = (short)h0; al0[jj] = (short)f2bf(xs0[jj] - bf2f(h0));
                ushort h1 = f2bf(xs1[jj]);
                ah1[jj] = (short)h1; al1[jj] = (short)f2bf(xs1[jj] - bf2f(h1));
            }
        }
        // prefetch next kc's A words (overlaps stage drain)
        if (kc < 7) {
            cx0a = *(const float4*)(xp + xbase0 + (kc + 1) * 32 + quad * 8);
            cx0b = *(const float4*)(xp + xbase0 + (kc + 1) * 32 + quad * 8 + 4);
            cx1a = *(const float4*)(xp + xbase1 + (kc + 1) * 32 + quad * 8);
            cx1b = *(const float4*)(xp + xbase1 + (kc + 1) * 32 + quad * 8 + 4);
        }
        __syncthreads();   // RAW: stage complete
#pragma unroll
        for (int t = 0; t < 16; t++) {
            int tq = h * 16 + t;
            short8 bh = *(const short8*)(lds + tq * 512 + L * 8);
            short8 bl = *(const short8*)(lds + (32 + tq) * 512 + L * 8);
            sc[0][t] = __builtin_amdgcn_mfma_f32_16x16x32_bf16(ah0, bh, sc[0][t], 0, 0, 0);
            sc[0][t] = __builtin_amdgcn_mfma_f32_16x16x32_bf16(ah0, bl, sc[0][t], 0, 0, 0);
            sc[0][t] = __builtin_amdgcn_mfma_f32_16x16x32_bf16(al0, bh, sc[0][t], 0, 0, 0);
            sc[1][t] = __builtin_amdgcn_mfma_f32_16x16x32_bf16(ah1, bh, sc[1][t], 0, 0, 0);
            sc[1][t] = __builtin_amdgcn_mfma_f32_16x16x32_bf16(ah1, bl, sc[1][t], 0, 0, 0);
            sc[1][t] = __builtin_amdgcn_mfma_f32_16x16x32_bf16(al1, bh, sc[1][t], 0, 0, 0);
        }
    }

    // ---------- Phase B: softmax (rows split q-wise across wave pairs) ----------
    __syncthreads();                 // all Phase A LDS reads done
    float* red = (float*)lds;        // [0..127]: max, [128..255]: sum
    float inv[2][4];
    float mx[2][4];
#pragma unroll
    for (int s = 0; s < 2; s++)
#pragma unroll
        for (int r = 0; r < 4; r++) {
            float pm = -1e30f;
#pragma unroll
            for (int t = 0; t < 16; t++) pm = fmaxf(pm, sc[s][t][r]);
#pragma unroll
            for (int mask = 1; mask <= 8; mask <<= 1) pm = fmaxf(pm, __shfl_xor(pm, mask));
            if (c == 0) red[(g * 32 + s * 16 + quad * 4 + r) * 2 + h] = pm;
        }
    __syncthreads();
#pragma unroll
    for (int s = 0; s < 2; s++)
#pragma unroll
        for (int r = 0; r < 4; r++) {
            int row = g * 32 + s * 16 + quad * 4 + r;
            mx[s][r] = fmaxf(red[row * 2], red[row * 2 + 1]);
            float ps = 0.f;
#pragma unroll
            for (int t = 0; t < 16; t++) {
                float e = __expf(sc[s][t][r] - mx[s][r]);
                sc[s][t][r] = e;
                ps += e;
            }
#pragma unroll
            for (int mask = 1; mask <= 8; mask <<= 1) ps += __shfl_xor(ps, mask);
            if (c == 0) red[128 + row * 2 + h] = ps;
        }
    __syncthreads();
#pragma unroll
    for (int s = 0; s < 2; s++)
#pragma unroll
        for (int r = 0; r < 4; r++) {
            int row = g * 32 + s * 16 + quad * 4 + r;
            inv[s][r] = 1.f / (red[128 + row * 2] + red[128 + row * 2 + 1]);
        }
    __syncthreads();                 // red reads done before alpha overwrites

    // alpha (bf16) -> LDS, xor-swizzled 8-elem chunks: row m 512 wide
#pragma unroll
    for (int s = 0; s < 2; s++)
#pragma unroll
        for (int r = 0; r < 4; r++) {
            int m_loc = g * 32 + s * 16 + quad * 4 + r;
            int swz = m_loc & 7;
            float iv = inv[s][r];
#pragma unroll
            for (int t = 0; t < 16; t++) {
                int q = h * 256 + t * 16 + c;
                lds[m_loc * 512 + (((q >> 3) ^ swz) << 3) + (c & 7)] = f2bf(sc[s][t][r] * iv);
            }
        }
    __syncthreads();

    // ---------- Phase C: oacc = alpha(LDS) @ yT(global, L2-hot) over k-half ----------
#pragma unroll
    for (int s = 0; s < 2; s++)
#pragma unroll
        for (int t = 0; t < 16; t++) sc[s][t] = (f32x4)0.f;   // reuse as oacc

    const int am0 = g * 32 + c;
    const int swzA = am0 & 7;        // (am0+16)&7 == am0&7
    for (int kc = 0; kc < 8; kc++) {
        int cq = h * 32 + kc * 4 + quad;
        short8 af0 = *(const short8*)(lds + am0 * 512 + ((cq ^ swzA) << 3));
        short8 af1 = *(const short8*)(lds + (am0 + 16) * 512 + ((cq ^ swzA) << 3));
        const ushort* yb = yT + (size_t)(b * D_ + c) * 512 + h * 256 + kc * 32 + quad * 8;
#pragma unroll
        for (int nt = 0; nt < 16; nt++) {
            short8 bfr = *(const short8*)(yb + (size_t)nt * 16 * 512);
            sc[0][nt] = __builtin_amdgcn_mfma_f32_16x16x32_bf16(af0, bfr, sc[0][nt], 0, 0, 0);
            sc[1][nt] = __builtin_amdgcn_mfma_f32_16x16x32_bf16(af1, bfr, sc[1][nt], 0, 0, 0);
        }
    }

    // ---------- partial-sum exchange (h=1 -> h=0) + store ----------
    __syncthreads();                 // all alpha reads done
    float* exch = (float*)lds;       // [64][256] f32, +rl*4 swizzle
    if (h == 1) {
#pragma unroll
        for (int s = 0; s < 2; s++)
#pragma unroll
            for (int nt = 0; nt < 16; nt++)
#pragma unroll
                for (int r = 0; r < 4; r++) {
                    int rl = g * 32 + s * 16 + quad * 4 + r;
                    int d = nt * 16 + c;
                    exch[rl * 256 + ((d + rl * 4) & 255)] = sc[s][nt][r];
                }
    }
    __syncthreads();
    if (h == 0) {
#pragma unroll
        for (int s = 0; s < 2; s++)
#pragma unroll
            for (int nt = 0; nt < 16; nt++)
#pragma unroll
                for (int r = 0; r < 4; r++) {
                    int rl = g * 32 + s * 16 + quad * 4 + r;
                    int d = nt * 16 + c;
                    float v = sc[s][nt][r] + exch[rl * 256 + ((d + rl * 4) & 255)];
                    out[(size_t)(b * LP_ + m0 + rl) * 256 + d] = v;
                }
    }
}

extern "C" void kernel_launch(void* const* d_in, const int* in_sizes, int n_in,
                              void* d_out, int out_size, void* d_ws, size_t ws_size,
                              hipStream_t stream) {
    const float* x    = (const float*)d_in[0];
    const float* y    = (const float*)d_in[1];
    const float* W    = (const float*)d_in[2];
    const float* bias = (const float*)d_in[3];
    float* out = (float*)d_out;

    char* ws = (char*)d_ws;
    size_t off = 0;
    ushort* Whi = (ushort*)(ws + off); off += (size_t)D_ * D_ * 2;
    ushort* Wlo = (ushort*)(ws + off); off += (size_t)D_ * D_ * 2;
    ushort* yT  = (ushort*)(ws + off); off += (size_t)B_ * D_ * LQ_ * 2;
    ushort* yph = (ushort*)(ws + off); off += (size_t)B_ * LQ_ * D_ * 2;
    ushort* ypl = (ushort*)(ws + off); off += (size_t)B_ * LQ_ * D_ * 2;
    float*  xp  = (float*)(ws + off);  off += (size_t)B_ * LP_ * D_ * 4;

    k_wsplit<<<(D_ * D_) / 256, 256, 0, stream>>>(W, Whi, Wlo);
    k_ytrans<<<B_ * 128, 256, 0, stream>>>(y, yT);
    k_proj<true><<<(B_ * LQ_) / 64, 256, 0, stream>>>(y, Whi, Wlo, bias, nullptr, yph, ypl);
    k_proj<false><<<(B_ * LP_) / 64, 256, 0, stream>>>(x, Whi, Wlo, bias, xp, nullptr, nullptr);
    k_attn<<<B_ * 32, 256, 0, stream>>>(xp, yph, ypl, yT, out);
}

// Round 3
// 345.801 us; speedup vs baseline: 1.5402x; 1.0316x over previous
//
#include <hip/hip_runtime.h>
#include <stdint.h>

// Problem constants (SeqAttnMatch): B=32, LP=2048, LQ=512, D=256, fp32 in/out.
#define B_  32
#define LP_ 2048
#define LQ_ 512
#define D_  256

typedef __attribute__((ext_vector_type(8))) short short8;   // 8 bf16 = 4 VGPRs
typedef __attribute__((ext_vector_type(4))) float f32x4;

// ---- bf16 helpers (RNE) ----
__device__ __forceinline__ ushort f2bf(float x) {
    union { float f; uint32_t u; } v; v.f = x;
    uint32_t r = v.u + 0x7FFFu + ((v.u >> 16) & 1u);
    return (ushort)(r >> 16);
}
__device__ __forceinline__ float bf2f(ushort h) {
    union { float f; uint32_t u; } v; v.u = ((uint32_t)h) << 16;
    return v.f;
}

// async global->LDS, 16B per lane. LDS base wave-uniform; HW writes lds+lane*16.
// Global source address is per-lane (gather OK).
__device__ __forceinline__ void gl_lds16(const void* g, void* l) {
    __builtin_amdgcn_global_load_lds(
        (const __attribute__((address_space(1))) void*)g,
        (__attribute__((address_space(3))) void*)l, 16, 0, 0);
}

// ---- K0a: split W (fp32 [256*256]) into hi/lo bf16 planes ----
__global__ void k_wsplit(const float* __restrict__ W,
                         ushort* __restrict__ Whi, ushort* __restrict__ Wlo) {
    int i = blockIdx.x * 256 + threadIdx.x;
    float w = W[i];
    ushort h = f2bf(w);
    Whi[i] = h;
    Wlo[i] = f2bf(w - bf2f(h));
}

// ---- K0b: transpose y [B][LQ][D] f32 -> yT [B][D][LQ] bf16 ----
__global__ void k_ytrans(const float* __restrict__ y, ushort* __restrict__ yT) {
    __shared__ float tile[32][33];
    int bid = blockIdx.x;            // B*16*8 = 4096 blocks
    int b  = bid >> 7;
    int t2 = bid & 127;
    int qt = t2 >> 3;
    int dt = t2 & 7;
    int q0 = qt * 32, d0 = dt * 32;
    int tid = threadIdx.x;
    int r  = tid >> 3;
    int c4 = (tid & 7) * 4;
    float4 v = *(const float4*)(y + ((size_t)(b * LQ_ + q0 + r) * D_ + d0 + c4));
    tile[r][c4 + 0] = v.x; tile[r][c4 + 1] = v.y;
    tile[r][c4 + 2] = v.z; tile[r][c4 + 3] = v.w;
    __syncthreads();
    ushort4 o;
    o.x = f2bf(tile[c4 + 0][r]);
    o.y = f2bf(tile[c4 + 1][r]);
    o.z = f2bf(tile[c4 + 2][r]);
    o.w = f2bf(tile[c4 + 3][r]);
    *(ushort4*)(yT + ((size_t)(b * D_ + d0 + r) * LQ_ + q0 + c4)) = o;
}

// ---- K1: proj = relu(A @ W^T + b) -> hi/lo bf16 planes ----
// 512 thr (8 waves), 128 rows/block, wave w rows [bid*128+16w, +16).
// W staged ping-pong (2 x 32KB) via global_load_lds; A prefetched one kc ahead.
__global__ __launch_bounds__(512, 4) void k_proj(const float* __restrict__ A,
                                                 const ushort* __restrict__ Whi,
                                                 const ushort* __restrict__ Wlo,
                                                 const float* __restrict__ bias,
                                                 ushort* __restrict__ Ohi,
                                                 ushort* __restrict__ Olo) {
    __shared__ ushort Ws[32768];   // 64KB = 2 x 32KB ping-pong
    const int tid  = threadIdx.x;
    const int w    = tid >> 6;      // 0..7
    const int L    = tid & 63;
    const int c    = L & 15;
    const int quad = L >> 4;
    const int row0 = blockIdx.x * 128 + w * 16;
    const int arow = row0 + c;

    f32x4 acc[16];
#pragma unroll
    for (int i = 0; i < 16; i++) acc[i] = (f32x4)0.f;

    // stage unit kc (32KB: 32 x 1KB frag blocks, i = plane*16+nt) into half p
#define PROJ_STAGE(kc, p)                                                      \
    {                                                                          \
        _Pragma("unroll")                                                      \
        for (int ii = 0; ii < 4; ii++) {                                       \
            int i = w * 4 + ii;                                                \
            const ushort* src = ((i >> 4) ? Wlo : Whi) +                       \
                ((size_t)((i & 15) * 16 + c) * 256 + (kc) * 32 + quad * 8);    \
            gl_lds16(src, (char*)Ws + (p) * 32768 + i * 1024);                 \
        }                                                                      \
    }

    PROJ_STAGE(0, 0);
    float4 nx0 = *(const float4*)(A + (size_t)arow * 256 + quad * 8);
    float4 nx1 = *(const float4*)(A + (size_t)arow * 256 + quad * 8 + 4);

    for (int kc = 0; kc < 8; kc++) {
        __syncthreads();             // publishes stage(kc); prior reads of other half done
        if (kc < 7) PROJ_STAGE(kc + 1, (kc + 1) & 1);
        float4 cx0 = nx0, cx1 = nx1;
        if (kc < 7) {
            nx0 = *(const float4*)(A + (size_t)arow * 256 + (kc + 1) * 32 + quad * 8);
            nx1 = *(const float4*)(A + (size_t)arow * 256 + (kc + 1) * 32 + quad * 8 + 4);
        }
        float xs[8] = {cx0.x, cx0.y, cx0.z, cx0.w, cx1.x, cx1.y, cx1.z, cx1.w};
        short8 ah;
#pragma unroll
        for (int j = 0; j < 8; j++) ah[j] = (short)f2bf(xs[j]);
        const ushort* buf = Ws + (kc & 1) * 16384;
#pragma unroll
        for (int nt = 0; nt < 16; nt++) {
            short8 bh = *(const short8*)(buf + nt * 512 + L * 8);
            short8 bl = *(const short8*)(buf + (16 + nt) * 512 + L * 8);
            acc[nt] = __builtin_amdgcn_mfma_f32_16x16x32_bf16(ah, bh, acc[nt], 0, 0, 0);
            acc[nt] = __builtin_amdgcn_mfma_f32_16x16x32_bf16(ah, bl, acc[nt], 0, 0, 0);
        }
    }
#pragma unroll
    for (int nt = 0; nt < 16; nt++) {
        const int e = nt * 16 + c;
        const float bv = bias[e];
#pragma unroll
        for (int r = 0; r < 4; r++) {
            const int grow = row0 + quad * 4 + r;
            float v = acc[nt][r] + bv;
            v = fmaxf(v, 0.f);
            ushort h = f2bf(v);
            Ohi[(size_t)grow * 256 + e] = h;
            Olo[(size_t)grow * 256 + e] = f2bf(v - bf2f(h));
        }
    }
}

// ---- K3: fused scores (split-bf16) + softmax + match (bf16) ----
// Block = (batch, 64 x-rows), 4 waves. Wave (g = w&1, h = w>>1):
//   rows m0 + g*32 + [0,32), q-half h*256 + [0,256).
// Phase A: 16 stage units (kc, q-half) of 32KB, ping-pong double-buffered;
// wave h computes on units with parity h while the next unit streams in.
__global__ __launch_bounds__(256, 2) void k_attn(const ushort* __restrict__ xph,
                                                 const ushort* __restrict__ xpl,
                                                 const ushort* __restrict__ yph,
                                                 const ushort* __restrict__ ypl,
                                                 const ushort* __restrict__ yT,
                                                 float* __restrict__ out) {
    __shared__ ushort lds[32768];   // 64KB: Phase A = 2x32KB ping-pong; then alpha
    const int tid  = threadIdx.x;
    const int w    = tid >> 6;
    const int L    = tid & 63;
    const int c    = L & 15;
    const int quad = L >> 4;
    const int g    = w & 1;
    const int h    = w >> 1;

    // XCD-affinity swizzle: XCD x sees only batches 4x..4x+3
    const int bid = blockIdx.x;
    const int j   = bid >> 3;
    const int b   = (bid & 7) * 4 + (j >> 5);
    const int mt  = j & 31;
    const int m0  = mt * 64;

    f32x4 sc[2][16];
#pragma unroll
    for (int s = 0; s < 2; s++)
#pragma unroll
        for (int t = 0; t < 16; t++) sc[s][t] = (f32x4)0.f;

    // ---------- Phase A ----------
    const size_t ar0 = (size_t)(b * LP_ + m0 + g * 32 + c) * 256;
    const size_t ar1 = ar0 + 16 * 256;

    // stage unit u: kc = u>>1, qh = u&1; 32 x 1KB blocks (i = plane*16 + tql)
#define ATTN_STAGE(u)                                                          \
    {                                                                          \
        const int kc_ = (u) >> 1, qh_ = (u) & 1, p_ = (u) & 1;                 \
        _Pragma("unroll")                                                      \
        for (int ii = 0; ii < 8; ii++) {                                       \
            int i = w * 8 + ii;                                                \
            const ushort* src = ((i >> 4) ? ypl : yph) +                       \
                ((size_t)(b * LQ_ + qh_ * 256 + (i & 15) * 16 + c) * 256 +     \
                 kc_ * 32 + quad * 8);                                         \
            gl_lds16(src, (char*)lds + p_ * 32768 + i * 1024);                 \
        }                                                                      \
    }

    // A-frag prefetch (kc=0)
    short8 nah0 = *(const short8*)(xph + ar0 + quad * 8);
    short8 nal0 = *(const short8*)(xpl + ar0 + quad * 8);
    short8 nah1 = *(const short8*)(xph + ar1 + quad * 8);
    short8 nal1 = *(const short8*)(xpl + ar1 + quad * 8);

    ATTN_STAGE(0);
    for (int u = 0; u < 16; u++) {
        __syncthreads();             // publish stage(u); reads of buf[(u+1)&1] (unit u-1) done
        if (u < 15) ATTN_STAGE(u + 1);
        if ((u & 1) == h) {
            const int kc = u >> 1;
            short8 ah0 = nah0, al0 = nal0, ah1 = nah1, al1 = nal1;
            if (kc < 7) {
                nah0 = *(const short8*)(xph + ar0 + (kc + 1) * 32 + quad * 8);
                nal0 = *(const short8*)(xpl + ar0 + (kc + 1) * 32 + quad * 8);
                nah1 = *(const short8*)(xph + ar1 + (kc + 1) * 32 + quad * 8);
                nal1 = *(const short8*)(xpl + ar1 + (kc + 1) * 32 + quad * 8);
            }
            const ushort* buf = lds + (u & 1) * 16384;
#pragma unroll
            for (int t = 0; t < 16; t++) {
                short8 bh = *(const short8*)(buf + t * 512 + L * 8);
                short8 bl = *(const short8*)(buf + (16 + t) * 512 + L * 8);
                sc[0][t] = __builtin_amdgcn_mfma_f32_16x16x32_bf16(ah0, bh, sc[0][t], 0, 0, 0);
                sc[0][t] = __builtin_amdgcn_mfma_f32_16x16x32_bf16(ah0, bl, sc[0][t], 0, 0, 0);
                sc[0][t] = __builtin_amdgcn_mfma_f32_16x16x32_bf16(al0, bh, sc[0][t], 0, 0, 0);
                sc[1][t] = __builtin_amdgcn_mfma_f32_16x16x32_bf16(ah1, bh, sc[1][t], 0, 0, 0);
                sc[1][t] = __builtin_amdgcn_mfma_f32_16x16x32_bf16(ah1, bl, sc[1][t], 0, 0, 0);
                sc[1][t] = __builtin_amdgcn_mfma_f32_16x16x32_bf16(al1, bh, sc[1][t], 0, 0, 0);
            }
        }
    }

    // ---------- Phase B: softmax (rows split q-wise across wave pairs) ----------
    __syncthreads();                 // all Phase A LDS reads done
    float* red = (float*)lds;        // [0..127]: max, [128..255]: sum
    float inv[2][4];
    float mx[2][4];
#pragma unroll
    for (int s = 0; s < 2; s++)
#pragma unroll
        for (int r = 0; r < 4; r++) {
            float pm = -1e30f;
#pragma unroll
            for (int t = 0; t < 16; t++) pm = fmaxf(pm, sc[s][t][r]);
#pragma unroll
            for (int mask = 1; mask <= 8; mask <<= 1) pm = fmaxf(pm, __shfl_xor(pm, mask));
            if (c == 0) red[(g * 32 + s * 16 + quad * 4 + r) * 2 + h] = pm;
        }
    __syncthreads();
#pragma unroll
    for (int s = 0; s < 2; s++)
#pragma unroll
        for (int r = 0; r < 4; r++) {
            int row = g * 32 + s * 16 + quad * 4 + r;
            mx[s][r] = fmaxf(red[row * 2], red[row * 2 + 1]);
            float ps = 0.f;
#pragma unroll
            for (int t = 0; t < 16; t++) {
                float e = __expf(sc[s][t][r] - mx[s][r]);
                sc[s][t][r] = e;
                ps += e;
            }
#pragma unroll
            for (int mask = 1; mask <= 8; mask <<= 1) ps += __shfl_xor(ps, mask);
            if (c == 0) red[128 + row * 2 + h] = ps;
        }
    __syncthreads();
#pragma unroll
    for (int s = 0; s < 2; s++)
#pragma unroll
        for (int r = 0; r < 4; r++) {
            int row = g * 32 + s * 16 + quad * 4 + r;
            inv[s][r] = 1.f / (red[128 + row * 2] + red[128 + row * 2 + 1]);
        }
    __syncthreads();                 // red reads done before alpha overwrites

    // alpha (bf16) -> LDS, xor-swizzled 8-elem chunks: row m 512 wide
#pragma unroll
    for (int s = 0; s < 2; s++)
#pragma unroll
        for (int r = 0; r < 4; r++) {
            int m_loc = g * 32 + s * 16 + quad * 4 + r;
            int swz = m_loc & 7;
            float iv = inv[s][r];
#pragma unroll
            for (int t = 0; t < 16; t++) {
                int q = h * 256 + t * 16 + c;
                lds[m_loc * 512 + (((q >> 3) ^ swz) << 3) + (c & 7)] = f2bf(sc[s][t][r] * iv);
            }
        }
    __syncthreads();

    // ---------- Phase C: oacc = alpha(LDS) @ yT(global, L2-hot) over k-half ----------
#pragma unroll
    for (int s = 0; s < 2; s++)
#pragma unroll
        for (int t = 0; t < 16; t++) sc[s][t] = (f32x4)0.f;   // reuse as oacc

    const int am0 = g * 32 + c;
    const int swzA = am0 & 7;        // (am0+16)&7 == am0&7
    for (int kc = 0; kc < 8; kc++) {
        int cq = h * 32 + kc * 4 + quad;
        short8 af0 = *(const short8*)(lds + am0 * 512 + ((cq ^ swzA) << 3));
        short8 af1 = *(const short8*)(lds + (am0 + 16) * 512 + ((cq ^ swzA) << 3));
        const ushort* yb = yT + (size_t)(b * D_ + c) * 512 + h * 256 + kc * 32 + quad * 8;
#pragma unroll
        for (int nt = 0; nt < 16; nt++) {
            short8 bfr = *(const short8*)(yb + (size_t)nt * 16 * 512);
            sc[0][nt] = __builtin_amdgcn_mfma_f32_16x16x32_bf16(af0, bfr, sc[0][nt], 0, 0, 0);
            sc[1][nt] = __builtin_amdgcn_mfma_f32_16x16x32_bf16(af1, bfr, sc[1][nt], 0, 0, 0);
        }
    }

    // ---------- partial-sum exchange (h=1 -> h=0) + store ----------
    __syncthreads();                 // all alpha reads done
    float* exch = (float*)lds;       // [64][256] f32, +rl*4 swizzle
    if (h == 1) {
#pragma unroll
        for (int s = 0; s < 2; s++)
#pragma unroll
            for (int nt = 0; nt < 16; nt++)
#pragma unroll
                for (int r = 0; r < 4; r++) {
                    int rl = g * 32 + s * 16 + quad * 4 + r;
                    int d = nt * 16 + c;
                    exch[rl * 256 + ((d + rl * 4) & 255)] = sc[s][nt][r];
                }
    }
    __syncthreads();
    if (h == 0) {
#pragma unroll
        for (int s = 0; s < 2; s++)
#pragma unroll
            for (int nt = 0; nt < 16; nt++)
#pragma unroll
                for (int r = 0; r < 4; r++) {
                    int rl = g * 32 + s * 16 + quad * 4 + r;
                    int d = nt * 16 + c;
                    float v = sc[s][nt][r] + exch[rl * 256 + ((d + rl * 4) & 255)];
                    out[(size_t)(b * LP_ + m0 + rl) * 256 + d] = v;
                }
    }
}

extern "C" void kernel_launch(void* const* d_in, const int* in_sizes, int n_in,
                              void* d_out, int out_size, void* d_ws, size_t ws_size,
                              hipStream_t stream) {
    const float* x    = (const float*)d_in[0];
    const float* y    = (const float*)d_in[1];
    const float* W    = (const float*)d_in[2];
    const float* bias = (const float*)d_in[3];
    float* out = (float*)d_out;

    char* ws = (char*)d_ws;
    size_t off = 0;
    ushort* Whi = (ushort*)(ws + off); off += (size_t)D_ * D_ * 2;
    ushort* Wlo = (ushort*)(ws + off); off += (size_t)D_ * D_ * 2;
    ushort* yT  = (ushort*)(ws + off); off += (size_t)B_ * D_ * LQ_ * 2;
    ushort* yph = (ushort*)(ws + off); off += (size_t)B_ * LQ_ * D_ * 2;
    ushort* ypl = (ushort*)(ws + off); off += (size_t)B_ * LQ_ * D_ * 2;
    ushort* xph = (ushort*)(ws + off); off += (size_t)B_ * LP_ * D_ * 2;
    ushort* xpl = (ushort*)(ws + off); off += (size_t)B_ * LP_ * D_ * 2;

    k_wsplit<<<(D_ * D_) / 256, 256, 0, stream>>>(W, Whi, Wlo);
    k_ytrans<<<B_ * 128, 256, 0, stream>>>(y, yT);
    k_proj<<<(B_ * LQ_) / 128, 512, 0, stream>>>(y, Whi, Wlo, bias, yph, ypl);
    k_proj<<<(B_ * LP_) / 128, 512, 0, stream>>>(x, Whi, Wlo, bias, xph, xpl);
    k_attn<<<B_ * 32, 256, 0, stream>>>(xph, xpl, yph, ypl, yT, out);
}

// Round 4
// 273.274 us; speedup vs baseline: 1.9490x; 1.2654x over previous
//
#include <hip/hip_runtime.h>
#include <stdint.h>

// SeqAttnMatch: B=32, LP=2048, LQ=512, D=256, fp32 in/out.
#define B_  32
#define LP_ 2048
#define LQ_ 512
#define D_  256

typedef __attribute__((ext_vector_type(8))) short short8;   // 8 bf16 = 4 VGPRs
typedef __attribute__((ext_vector_type(4))) float f32x4;

__device__ __forceinline__ ushort f2bf(float x) {
    union { float f; uint32_t u; } v; v.f = x;
    uint32_t r = v.u + 0x7FFFu + ((v.u >> 16) & 1u);
    return (ushort)(r >> 16);
}
__device__ __forceinline__ float bf2f(ushort h) {
    union { float f; uint32_t u; } v; v.u = ((uint32_t)h) << 16;
    return v.f;
}
// async global->LDS, 16B/lane; HW writes lds + lane*16. Contiguous src = fast path.
__device__ __forceinline__ void gl_lds16(const void* g, void* l) {
    __builtin_amdgcn_global_load_lds(
        (const __attribute__((address_space(1))) void*)g,
        (__attribute__((address_space(3))) void*)l, 16, 0, 0);
}

// Fragment-blocked layout: 1KB blocks of 512 ushorts. Element for lane
// L=quad*16+c, byte position L*16 + j*2, holds M[row_tile*16 + c][k0 + quad*8 + j].

// ---- K0a: W [e][k] f32 -> frag-blocked hi/lo. Block (kc=k/32, nt=e/16) at (kc*16+nt). ----
__global__ void k_wsplit(const float* __restrict__ W,
                         ushort* __restrict__ Whf, ushort* __restrict__ Wlf) {
    int i = blockIdx.x * 256 + threadIdx.x;
    int e = i >> 8, k = i & 255;
    float w = W[i];
    ushort h = f2bf(w);
    size_t off = (size_t)((k >> 5) * 16 + (e >> 4)) * 512 +
                 ((k >> 3) & 3) * 128 + (e & 15) * 8 + (k & 7);
    Whf[off] = h;
    Wlf[off] = f2bf(w - bf2f(h));
}

// ---- K0b: y [b][q][d] f32 -> yf frag-blocked bf16 (Phase-C B operand: k=q, n=d). ----
// Block (b, qc=q/32, nt=d/16) at b*256 + qc*16 + nt; lane (c,quad,j) = y[qc*32+quad*8+j][nt*16+c].
__global__ void k_ytrans(const float* __restrict__ y, ushort* __restrict__ yf) {
    __shared__ float t[32 * 260];
    int bid = blockIdx.x;            // 32*16 = 512
    int b = bid >> 4, qc = bid & 15;
    int tid = threadIdx.x;
    int ql = tid >> 3;               // 0..31
    int d0 = (tid & 7) * 4;
#pragma unroll
    for (int p = 0; p < 8; p++) {
        int d = p * 32 + d0;
        float4 v = *(const float4*)(y + ((size_t)(b * LQ_ + qc * 32 + ql) * 256 + d));
        t[ql * 260 + d + 0] = v.x; t[ql * 260 + d + 1] = v.y;
        t[ql * 260 + d + 2] = v.z; t[ql * 260 + d + 3] = v.w;
    }
    __syncthreads();
    int w = tid >> 6, L = tid & 63, c = L & 15, quad = L >> 4;
#pragma unroll
    for (int ii = 0; ii < 4; ii++) {
        int nt = w * 4 + ii;
        short8 o;
#pragma unroll
        for (int j = 0; j < 8; j++)
            o[j] = (short)f2bf(t[(quad * 8 + j) * 260 + nt * 16 + c]);
        *(short8*)(yf + ((size_t)(b * 256 + qc * 16 + nt) * 512 + L * 8)) = o;
    }
}

// ---- K1: proj = relu(A @ W^T + b) -> frag-blocked hi/lo bf16 planes ----
// 256 thr (4 waves), 64 rows/block, wave w rows [blk*64+16w, +16).
// XL=true: x layout, block idx = rt_g*8 + ec. XL=false: y layout, (rt_g>>5)*256 + ec*32 + (rt_g&31).
template <bool XL>
__global__ __launch_bounds__(256, 2) void k_proj(const float* __restrict__ A,
                                                 const ushort* __restrict__ Whf,
                                                 const ushort* __restrict__ Wlf,
                                                 const float* __restrict__ bias,
                                                 ushort* __restrict__ Ohi,
                                                 ushort* __restrict__ Olo) {
    __shared__ __align__(16) ushort Ws[32768];   // 64KB: 2x32KB ping-pong, then transpose scratch
    const int tid  = threadIdx.x;
    const int w    = tid >> 6;
    const int L    = tid & 63;
    const int c    = L & 15;
    const int quad = L >> 4;
    const int row0 = blockIdx.x * 64 + w * 16;
    const int arow = row0 + c;

    f32x4 acc[16];
#pragma unroll
    for (int i = 0; i < 16; i++) acc[i] = (f32x4)0.f;

    // stage unit kc: hi 16KB + lo 16KB, fully contiguous DMA
#define PSTAGE(kc, p)                                                          \
    {                                                                          \
        _Pragma("unroll")                                                      \
        for (int ii = 0; ii < 8; ii++) {                                       \
            int i = w * 8 + ii;                                                \
            const ushort* src = ((i < 16) ? Whf : Wlf) + (size_t)(kc) * 8192 + \
                                (i & 15) * 512 + L * 8;                        \
            gl_lds16(src, (char*)Ws + (p) * 32768 + i * 1024);                 \
        }                                                                      \
    }

    PSTAGE(0, 0);
    float4 nx0 = *(const float4*)(A + (size_t)arow * 256 + quad * 8);
    float4 nx1 = *(const float4*)(A + (size_t)arow * 256 + quad * 8 + 4);

    for (int kc = 0; kc < 8; kc++) {
        __syncthreads();
        if (kc < 7) PSTAGE(kc + 1, (kc + 1) & 1);
        float4 cx0 = nx0, cx1 = nx1;
        if (kc < 7) {
            nx0 = *(const float4*)(A + (size_t)arow * 256 + (kc + 1) * 32 + quad * 8);
            nx1 = *(const float4*)(A + (size_t)arow * 256 + (kc + 1) * 32 + quad * 8 + 4);
        }
        float xs[8] = {cx0.x, cx0.y, cx0.z, cx0.w, cx1.x, cx1.y, cx1.z, cx1.w};
        short8 ah;
#pragma unroll
        for (int j = 0; j < 8; j++) ah[j] = (short)f2bf(xs[j]);
        const ushort* buf = Ws + (kc & 1) * 16384;
#pragma unroll
        for (int nt = 0; nt < 16; nt++) {
            short8 bh = *(const short8*)(buf + nt * 512 + L * 8);
            short8 bl = *(const short8*)(buf + (16 + nt) * 512 + L * 8);
            acc[nt] = __builtin_amdgcn_mfma_f32_16x16x32_bf16(ah, bh, acc[nt], 0, 0, 0);
            acc[nt] = __builtin_amdgcn_mfma_f32_16x16x32_bf16(ah, bl, acc[nt], 0, 0, 0);
        }
    }

    // epilogue: bias+relu, per-wave LDS transpose C-layout -> A-frag layout, coalesced stores
    __syncthreads();                 // all waves done reading Ws
    float* tr = (float*)Ws + w * (16 * 130);   // 16 rows x 130 f32 per wave
    const int rt_g = row0 >> 4;
#pragma unroll
    for (int half = 0; half < 2; half++) {
#pragma unroll
        for (int nt8 = 0; nt8 < 8; nt8++) {
            int nt = half * 8 + nt8;
            float bv = bias[nt * 16 + c];
#pragma unroll
            for (int r = 0; r < 4; r++)
                tr[(quad * 4 + r) * 130 + nt8 * 16 + c] = fmaxf(acc[nt][r] + bv, 0.f);
        }
#pragma unroll
        for (int ec4 = 0; ec4 < 4; ec4++) {
            int ec = half * 4 + ec4;
            short8 hh, ll;
#pragma unroll
            for (int j = 0; j < 8; j++) {
                float v = tr[c * 130 + ec4 * 32 + quad * 8 + j];
                ushort h = f2bf(v);
                hh[j] = (short)h;
                ll[j] = (short)f2bf(v - bf2f(h));
            }
            size_t blk = XL ? ((size_t)rt_g * 8 + ec)
                            : ((size_t)(rt_g >> 5) * 256 + ec * 32 + (rt_g & 31));
            *(short8*)(Ohi + blk * 512 + L * 8) = hh;
            *(short8*)(Olo + blk * 512 + L * 8) = ll;
        }
    }
}

// ---- K3: fused scores (split-bf16) + softmax + match (bf16) ----
// Block = (batch, 64 x-rows), 4 waves. Phase A: wave w = q-quarter w, ALL 64 rows
// (zero redundancy), barrier-free K-loop; x-frags pre-staged in LDS once.
// Phase C: wave (qh=w&1, dh=w>>1), zero redundancy.
__global__ __launch_bounds__(256, 2) void k_attn(const ushort* __restrict__ xphf,
                                                 const ushort* __restrict__ xplf,
                                                 const ushort* __restrict__ yphf,
                                                 const ushort* __restrict__ yplf,
                                                 const ushort* __restrict__ yf,
                                                 float* __restrict__ out) {
    __shared__ __align__(16) ushort lds[32768];   // 64KB
    const int tid  = threadIdx.x;
    const int w    = tid >> 6;
    const int L    = tid & 63;
    const int c    = L & 15;
    const int quad = L >> 4;

    // XCD-affinity swizzle: XCD x sees only batches 4x..4x+3
    const int bid = blockIdx.x;
    const int jj  = bid >> 3;
    const int b   = (bid & 7) * 4 + (jj >> 5);
    const int mt  = jj & 31;
    const int m0  = mt * 64;

    // ---- stage x-frags: 8 units (plane*4+rs) x 8 kc x 1KB, contiguous DMA ----
#pragma unroll
    for (int half = 0; half < 2; half++) {
        int pr = w * 2 + half;
        const ushort* base = ((pr < 4) ? xphf : xplf) +
                             ((size_t)(b * 128 + mt * 4 + (pr & 3)) * 8) * 512;
#pragma unroll
        for (int ii = 0; ii < 8; ii++)
            gl_lds16(base + ii * 512 + L * 8, (char*)lds + (pr * 8 + ii) * 1024);
    }

    f32x4 sc[4][8];
#pragma unroll
    for (int rs = 0; rs < 4; rs++)
#pragma unroll
        for (int t = 0; t < 8; t++) sc[rs][t] = (f32x4)0.f;
    __syncthreads();                 // x-frags visible; ONLY barrier before softmax

    // ---- Phase A: barrier-free. B-frags coalesced from L2-resident ypf. ----
    const ushort* ybh = yphf + (size_t)b * 256 * 512;
    const ushort* ybl = yplf + (size_t)b * 256 * 512;
    for (int kc = 0; kc < 8; kc++) {
        short8 ah[4], al[4];
#pragma unroll
        for (int rs = 0; rs < 4; rs++) {
            ah[rs] = *(const short8*)(lds + (rs * 8 + kc) * 512 + L * 8);
            al[rs] = *(const short8*)(lds + ((4 + rs) * 8 + kc) * 512 + L * 8);
        }
#pragma unroll
        for (int qt = 0; qt < 8; qt++) {
            size_t blk = ((size_t)kc * 32 + w * 8 + qt) * 512;
            short8 bh = *(const short8*)(ybh + blk + L * 8);
            short8 bl = *(const short8*)(ybl + blk + L * 8);
#pragma unroll
            for (int rs = 0; rs < 4; rs++) {
                sc[rs][qt] = __builtin_amdgcn_mfma_f32_16x16x32_bf16(ah[rs], bh, sc[rs][qt], 0, 0, 0);
                sc[rs][qt] = __builtin_amdgcn_mfma_f32_16x16x32_bf16(ah[rs], bl, sc[rs][qt], 0, 0, 0);
                sc[rs][qt] = __builtin_amdgcn_mfma_f32_16x16x32_bf16(al[rs], bh, sc[rs][qt], 0, 0, 0);
            }
        }
    }

    // ---- Phase B: softmax; each wave holds a q-quarter of every row ----
    __syncthreads();                 // x-frag reads done; lds reusable
    float* red  = (float*)lds;       // [64][4] partial max
    float* red2 = red + 256;         // [64][4] partial sum
    float inv[4][4];
#pragma unroll
    for (int rs = 0; rs < 4; rs++)
#pragma unroll
        for (int r = 0; r < 4; r++) {
            float pm = sc[rs][0][r];
#pragma unroll
            for (int qt = 1; qt < 8; qt++) pm = fmaxf(pm, sc[rs][qt][r]);
#pragma unroll
            for (int mask = 1; mask <= 8; mask <<= 1) pm = fmaxf(pm, __shfl_xor(pm, mask));
            if (c == 0) red[(rs * 16 + quad * 4 + r) * 4 + w] = pm;
        }
    __syncthreads();
#pragma unroll
    for (int rs = 0; rs < 4; rs++)
#pragma unroll
        for (int r = 0; r < 4; r++) {
            int row = rs * 16 + quad * 4 + r;
            float m = fmaxf(fmaxf(red[row * 4], red[row * 4 + 1]),
                            fmaxf(red[row * 4 + 2], red[row * 4 + 3]));
            float ps = 0.f;
#pragma unroll
            for (int qt = 0; qt < 8; qt++) {
                float e = __expf(sc[rs][qt][r] - m);
                sc[rs][qt][r] = e;
                ps += e;
            }
#pragma unroll
            for (int mask = 1; mask <= 8; mask <<= 1) ps += __shfl_xor(ps, mask);
            if (c == 0) red2[row * 4 + w] = ps;
        }
    __syncthreads();
#pragma unroll
    for (int rs = 0; rs < 4; rs++)
#pragma unroll
        for (int r = 0; r < 4; r++) {
            int row = rs * 16 + quad * 4 + r;
            inv[rs][r] = 1.f / (red2[row * 4] + red2[row * 4 + 1] +
                                red2[row * 4 + 2] + red2[row * 4 + 3]);
        }
    __syncthreads();                 // red/red2 reads done before alpha overwrites

    // alpha (bf16) -> LDS [64 rows][512 q], xor-swizzled 8-elem chunks
#pragma unroll
    for (int rs = 0; rs < 4; rs++)
#pragma unroll
        for (int r = 0; r < 4; r++) {
            int m_loc = rs * 16 + quad * 4 + r;
            int swz = m_loc & 7;
            float iv = inv[rs][r];
#pragma unroll
            for (int qt = 0; qt < 8; qt++) {
                int q = w * 128 + qt * 16 + c;
                lds[m_loc * 512 + (((q >> 3) ^ swz) << 3) + (c & 7)] = f2bf(sc[rs][qt][r] * iv);
            }
        }
    __syncthreads();

    // ---- Phase C: out = alpha(LDS) @ yf(global, coalesced). wave=(qh,dh). ----
#pragma unroll
    for (int rs = 0; rs < 4; rs++)
#pragma unroll
        for (int t = 0; t < 8; t++) sc[rs][t] = (f32x4)0.f;
    const int qh = w & 1, dh = w >> 1;
    const int swzA = c & 7;          // (rt*16+c)&7 == c&7
    for (int kcq = 0; kcq < 8; kcq++) {
        short8 af[4];
#pragma unroll
        for (int rt = 0; rt < 4; rt++) {
            int chunk = qh * 32 + kcq * 4 + quad;
            af[rt] = *(const short8*)(lds + (rt * 16 + c) * 512 + ((chunk ^ swzA) << 3));
        }
        const ushort* yb = yf + ((size_t)(b * 256 + (qh * 8 + kcq) * 16 + dh * 8)) * 512;
#pragma unroll
        for (int dt = 0; dt < 8; dt++) {
            short8 bfr = *(const short8*)(yb + dt * 512 + L * 8);
#pragma unroll
            for (int rs = 0; rs < 4; rs++)
                sc[rs][dt] = __builtin_amdgcn_mfma_f32_16x16x32_bf16(af[rs], bfr, sc[rs][dt], 0, 0, 0);
        }
    }

    // ---- partial-sum exchange (qh=1 -> qh=0) + store ----
    __syncthreads();                 // alpha reads done
    float* exch = (float*)lds;       // [2 dh][64][128], +row*4 swizzle
    if (qh == 1) {
#pragma unroll
        for (int rs = 0; rs < 4; rs++)
#pragma unroll
            for (int dt = 0; dt < 8; dt++)
#pragma unroll
                for (int r = 0; r < 4; r++) {
                    int row = rs * 16 + quad * 4 + r;
                    int dpr = dt * 16 + c;
                    exch[dh * 8192 + row * 128 + ((dpr + row * 4) & 127)] = sc[rs][dt][r];
                }
    }
    __syncthreads();
    if (qh == 0) {
#pragma unroll
        for (int rs = 0; rs < 4; rs++)
#pragma unroll
            for (int dt = 0; dt < 8; dt++)
#pragma unroll
                for (int r = 0; r < 4; r++) {
                    int row = rs * 16 + quad * 4 + r;
                    int dpr = dt * 16 + c;
                    float v = sc[rs][dt][r] + exch[dh * 8192 + row * 128 + ((dpr + row * 4) & 127)];
                    out[(size_t)(b * LP_ + m0 + row) * 256 + dh * 128 + dpr] = v;
                }
    }
}

extern "C" void kernel_launch(void* const* d_in, const int* in_sizes, int n_in,
                              void* d_out, int out_size, void* d_ws, size_t ws_size,
                              hipStream_t stream) {
    const float* x    = (const float*)d_in[0];
    const float* y    = (const float*)d_in[1];
    const float* W    = (const float*)d_in[2];
    const float* bias = (const float*)d_in[3];
    float* out = (float*)d_out;

    char* ws = (char*)d_ws;
    size_t off = 0;
    ushort* Whf  = (ushort*)(ws + off); off += (size_t)D_ * D_ * 2;          // 128KB
    ushort* Wlf  = (ushort*)(ws + off); off += (size_t)D_ * D_ * 2;
    ushort* yfb  = (ushort*)(ws + off); off += (size_t)B_ * D_ * LQ_ * 2;    // 8MB
    ushort* yphf = (ushort*)(ws + off); off += (size_t)B_ * LQ_ * D_ * 2;    // 8MB
    ushort* yplf = (ushort*)(ws + off); off += (size_t)B_ * LQ_ * D_ * 2;
    ushort* xphf = (ushort*)(ws + off); off += (size_t)B_ * LP_ * D_ * 2;    // 32MB
    ushort* xplf = (ushort*)(ws + off); off += (size_t)B_ * LP_ * D_ * 2;

    k_wsplit<<<(D_ * D_) / 256, 256, 0, stream>>>(W, Whf, Wlf);
    k_ytrans<<<B_ * 16, 256, 0, stream>>>(y, yfb);
    k_proj<false><<<(B_ * LQ_) / 64, 256, 0, stream>>>(y, Whf, Wlf, bias, yphf, yplf);
    k_proj<true><<<(B_ * LP_) / 64, 256, 0, stream>>>(x, Whf, Wlf, bias, xphf, xplf);
    k_attn<<<B_ * 32, 256, 0, stream>>>(xphf, xplf, yphf, yplf, yfb, out);
}